// Round 1
// baseline (58.988 us; speedup 1.0000x reference)
//
#include <hip/hip_runtime.h>

// Problem geometry (from reference setup_inputs):
//   x: [2, 2, 8, 64, 64, 64] float32 (0/1 values)
//   -> 2048 images of 64x64; count 4-connected components per image;
//   -> sum per group of 64 images, integer-divide by 64, output 32 floats.
constexpr int H = 64;
constexpr int W = 64;
constexpr int NPIX = H * W;       // 4096
constexpr int PATCHES = 64;       // images per output group
constexpr int NGROUPS = 32;       // 2*2*8

__device__ __forceinline__ int find_root(volatile int* p, int i) {
    int pi = p[i];
    while (pi != i) { i = pi; pi = p[i]; }
    return i;
}

// Concurrent union-find union: attach larger root under smaller root.
// CAS-retry guarantees no lost unions; min index of each component
// always remains a root -> #roots == #components (deterministic).
__device__ __forceinline__ void unite(int* p, int a, int b) {
    int ra = find_root(p, a);
    int rb = find_root(p, b);
    while (ra != rb) {
        if (ra < rb) { int t = ra; ra = rb; rb = t; }  // ra = hi, rb = lo
        int old = atomicCAS(&p[ra], ra, rb);
        if (old == ra) break;          // successfully attached
        ra = find_root(p, old);        // root moved; retry
        rb = find_root(p, rb);
    }
}

__global__ __launch_bounds__(256) void cc_kernel(const float* __restrict__ in,
                                                 int* __restrict__ group_sums) {
    __shared__ int par[NPIX];  // 16 KB
    const int img = blockIdx.x;
    const int tid = threadIdx.x;
    const float* src = in + (size_t)img * NPIX;

    // ---- load + init parents (coalesced float4) ----
#pragma unroll
    for (int k = 0; k < 4; ++k) {
        int v4 = k * 256 + tid;  // float4 index within image, 0..1023
        float4 f = reinterpret_cast<const float4*>(src)[v4];
        int base = v4 * 4;
        par[base + 0] = (f.x > 0.5f) ? (base + 0) : -1;
        par[base + 1] = (f.y > 0.5f) ? (base + 1) : -1;
        par[base + 2] = (f.z > 0.5f) ? (base + 2) : -1;
        par[base + 3] = (f.w > 0.5f) ? (base + 3) : -1;
    }
    __syncthreads();

    // ---- union with right & down neighbors ----
    // fg-ness test via par[j] >= 0 is stable under concurrent unions
    // (fg entries only ever hold nonnegative root indices).
    for (int k = 0; k < 16; ++k) {
        int i = k * 256 + tid;
        if (par[i] < 0) continue;
        int x = i & (W - 1);
        if (x + 1 < W && par[i + 1] >= 0) unite(par, i, i + 1);
        if (i + W < NPIX && par[i + W] >= 0) unite(par, i, i + W);
    }
    __syncthreads();

    // ---- count roots ----
    int cnt = 0;
#pragma unroll
    for (int k = 0; k < 16; ++k) {
        int i = k * 256 + tid;
        cnt += (par[i] == i) ? 1 : 0;
    }
    // wave (64-lane) reduction
#pragma unroll
    for (int off = 32; off > 0; off >>= 1) cnt += __shfl_down(cnt, off, 64);

    __shared__ int wsum[4];
    if ((tid & 63) == 0) wsum[tid >> 6] = cnt;
    __syncthreads();
    if (tid == 0) {
        int total = wsum[0] + wsum[1] + wsum[2] + wsum[3];
        atomicAdd(&group_sums[img / PATCHES], total);
    }
}

__global__ void finalize_kernel(const int* __restrict__ group_sums,
                                float* __restrict__ out, int ngroups) {
    int g = threadIdx.x + blockIdx.x * blockDim.x;
    if (g < ngroups) out[g] = (float)(group_sums[g] / PATCHES);
}

extern "C" void kernel_launch(void* const* d_in, const int* in_sizes, int n_in,
                              void* d_out, int out_size, void* d_ws, size_t ws_size,
                              hipStream_t stream) {
    const float* x = (const float*)d_in[0];
    float* out = (float*)d_out;
    int* ws = (int*)d_ws;

    const int nimg = in_sizes[0] / NPIX;      // 2048
    const int ngroups = out_size;             // 32

    hipMemsetAsync(ws, 0, ngroups * sizeof(int), stream);
    cc_kernel<<<nimg, 256, 0, stream>>>(x, ws);
    finalize_kernel<<<1, 64, 0, stream>>>(ws, out, ngroups);
}

// Round 2
// 43.745 us; speedup vs baseline: 1.3484x; 1.3484x over previous
//
#include <hip/hip_runtime.h>

// x: [2,2,8,64,64,64] fp32 0/1 -> 2048 images of 64x64.
// Count 4-connected components per image; per group of 64 images: sum // 64 -> float.
// Strategy: one 64-lane wave per image; lane r holds row r as a 64-bit mask.
// Horizontal runs are free (bitmask); union-find over runs (<=32/row) in LDS.
constexpr int NPIX = 64 * 64;
constexpr int PATCHES = 64;
constexpr int RUNS_PER_ROW = 32;
constexpr int TABLE = 64 * RUNS_PER_ROW;  // 2048 run slots per image
constexpr int IMGS_PER_BLOCK = 4;         // 4 waves per 256-thread block

__device__ __forceinline__ int find_root(volatile int* p, int i) {
    int pi = p[i];
    while (pi != i) { i = pi; pi = p[i]; }
    return i;
}

// Attach larger root under smaller (min run-id of each component stays root
// -> root count == component count, order-independent & deterministic).
__device__ __forceinline__ void unite(int* p, int a, int b) {
    int ra = find_root(p, a), rb = find_root(p, b);
    while (ra != rb) {
        if (ra < rb) { int t = ra; ra = rb; rb = t; }  // ra = larger
        int old = atomicCAS(&p[ra], ra, rb);
        if (old == ra) break;
        ra = find_root(p, old);
        rb = find_root(p, rb);
    }
}

__global__ __launch_bounds__(256) void cc_kernel(const float* __restrict__ in,
                                                 int* __restrict__ group_sums) {
    __shared__ int par_all[IMGS_PER_BLOCK][TABLE];  // 32 KB
    const int wid = threadIdx.x >> 6;
    const int lane = threadIdx.x & 63;
    const int img = blockIdx.x * IMGS_PER_BLOCK + wid;
    int* par = par_all[wid];
    const float* src = in + (size_t)img * NPIX;

    // ---- build row bitmasks: lane r ends with mask of row r ----
    unsigned long long m = 0;
#pragma unroll
    for (int j = 0; j < 64; ++j) {
        float v = src[j * 64 + lane];                 // coalesced 256B per wave
        unsigned long long b = __ballot(v > 0.5f);    // row j's mask, all lanes
        if (lane == j) m = b;
    }

    const unsigned long long s = m & ~(m << 1);       // run-start bits
    const int nrun = __popcll(s);

    // ---- init run table (lane-linear: conflict-free) ----
    for (int q = 0; q < TABLE / 64; ++q) {
        int t = q * 64 + lane;
        int nr = __shfl(nrun, t >> 5, 64);            // runs in row t>>5
        par[t] = ((t & 31) < nr) ? t : -1;
    }
    __syncthreads();

    // ---- vertical unions: lane r merges rows r and r+1 at overlap starts ----
    unsigned long long mn = __shfl_down(m, 1, 64);
    unsigned long long sn = __shfl_down(s, 1, 64);
    if (lane < 63) {
        unsigned long long both = m & mn;
        unsigned long long ov = both & ~(both << 1);  // one union per overlap segment
        while (ov) {
            int x = __builtin_ctzll(ov);
            ov &= ov - 1;
            unsigned long long below = (2ull << x) - 1;   // bits 0..x (x<=63 ok)
            int ida = lane * RUNS_PER_ROW + __popcll(s & below) - 1;
            int idb = (lane + 1) * RUNS_PER_ROW + __popcll(sn & below) - 1;
            unite(par, ida, idb);
        }
    }
    __syncthreads();

    // ---- count roots (lane-linear reads) ----
    int cnt = 0;
    for (int q = 0; q < TABLE / 64; ++q) {
        int t = q * 64 + lane;
        cnt += (par[t] == t) ? 1 : 0;
    }
#pragma unroll
    for (int d = 32; d > 0; d >>= 1) cnt += __shfl_xor(cnt, d, 64);
    if (lane == 0) atomicAdd(&group_sums[img / PATCHES], cnt);
}

__global__ void finalize_kernel(const int* __restrict__ group_sums,
                                float* __restrict__ out, int ngroups) {
    int g = threadIdx.x + blockIdx.x * blockDim.x;
    if (g < ngroups) out[g] = (float)(group_sums[g] / PATCHES);
}

extern "C" void kernel_launch(void* const* d_in, const int* in_sizes, int n_in,
                              void* d_out, int out_size, void* d_ws, size_t ws_size,
                              hipStream_t stream) {
    const float* x = (const float*)d_in[0];
    float* out = (float*)d_out;
    int* ws = (int*)d_ws;

    const int nimg = in_sizes[0] / NPIX;              // 2048
    const int ngroups = out_size;                     // 32

    hipMemsetAsync(ws, 0, ngroups * sizeof(int), stream);
    cc_kernel<<<nimg / IMGS_PER_BLOCK, 256, 0, stream>>>(x, ws);
    finalize_kernel<<<1, 64, 0, stream>>>(ws, out, ngroups);
}

// Round 3
// 43.144 us; speedup vs baseline: 1.3672x; 1.0139x over previous
//
#include <hip/hip_runtime.h>

// x: [2,2,8,64,64,64] fp32 0/1 -> 2048 images of 64x64.
// Per image: #4-connected components; per group of 64 images: sum // 64 -> float.
//
// One 64-lane wave per image. Lane r holds row r as a 64-bit mask (built via
// ballot). Horizontal runs are free; union-find over runs (id = row*32+rank)
// in an LDS table. components = total_runs - successful_merges, so no root
// scan is needed and unused table slots can stay as identity roots.
constexpr int NPIX = 64 * 64;
constexpr int PATCHES = 64;
constexpr int RUNS_PER_ROW = 32;
constexpr int TABLE = 64 * RUNS_PER_ROW;  // 2048 slots per image (worst case)
constexpr int IMGS_PER_BLOCK = 4;         // 4 waves / 256-thread block, 32 KB LDS

// Find with path halving. Benign race: halving writes p[i]=grandparent only on
// non-root i, always pointing to an ancestor -> safe under concurrency.
__device__ __forceinline__ int find_root(volatile int* p, int i) {
    while (true) {
        int pi = p[i];
        if (pi == i) return i;
        int gp = p[pi];
        if (gp == pi) return pi;
        p[i] = gp;  // halve
        i = gp;
    }
}

// Attach larger root under smaller. Parents strictly decrease -> acyclic, and
// each CAS win joins two distinct trees (stale rb chain ends < ra). Returns
// 1 iff this call performed a merge.
__device__ __forceinline__ int unite(int* p, int a, int b) {
    int ra = find_root(p, a), rb = find_root(p, b);
    while (ra != rb) {
        if (ra < rb) { int t = ra; ra = rb; rb = t; }  // ra = larger
        int old = atomicCAS(&p[ra], ra, rb);
        if (old == ra) return 1;
        ra = find_root(p, old);
        rb = find_root(p, rb);
    }
    return 0;
}

__global__ __launch_bounds__(256) void cc_kernel(const float* __restrict__ in,
                                                 int* __restrict__ group_sums) {
    __shared__ int par_all[IMGS_PER_BLOCK][TABLE];  // 32 KB
    const int wid = threadIdx.x >> 6;
    const int lane = threadIdx.x & 63;
    const int img = blockIdx.x * IMGS_PER_BLOCK + wid;
    int* par = par_all[wid];
    const float* src = in + (size_t)img * NPIX;

    // ---- identity-init whole table: 8 x ds_write_b128, contiguous ----
#pragma unroll
    for (int q = 0; q < TABLE / 256; ++q) {
        int base = q * 256 + lane * 4;
        int4 v = make_int4(base, base + 1, base + 2, base + 3);
        *reinterpret_cast<int4*>(&par[base]) = v;
    }

    // ---- build row bitmasks: lane r ends with mask of row r ----
    unsigned long long m = 0;
#pragma unroll
    for (int j = 0; j < 64; ++j) {
        float v = src[j * 64 + lane];                 // coalesced 256B/wave
        unsigned long long b = __ballot(v > 0.5f);    // row j's mask
        if (lane == j) m = b;
    }

    const unsigned long long s = m & ~(m << 1);       // run-start bits
    const int nrun = __popcll(s);

    __syncthreads();  // table visible before unions

    // ---- vertical unions: lane r merges rows r, r+1 at overlap starts ----
    int merges = 0;
    unsigned long long mn = __shfl_down(m, 1, 64);
    unsigned long long sn = __shfl_down(s, 1, 64);
    if (lane < 63) {
        unsigned long long both = m & mn;
        unsigned long long ov = both & ~(both << 1);  // one union per segment
        while (ov) {
            int x = __builtin_ctzll(ov);
            ov &= ov - 1;
            unsigned long long below = (2ull << x) - 1;  // bits 0..x
            int ida = lane * RUNS_PER_ROW + __popcll(s & below) - 1;
            int idb = (lane + 1) * RUNS_PER_ROW + __popcll(sn & below) - 1;
            merges += unite(par, ida, idb);
        }
    }

    // ---- components = runs - merges; wave-reduce both at once ----
    int cnt = nrun - merges;
#pragma unroll
    for (int d = 32; d > 0; d >>= 1) cnt += __shfl_xor(cnt, d, 64);
    if (lane == 0) atomicAdd(&group_sums[img / PATCHES], cnt);
}

__global__ void finalize_kernel(const int* __restrict__ group_sums,
                                float* __restrict__ out, int ngroups) {
    int g = threadIdx.x + blockIdx.x * blockDim.x;
    if (g < ngroups) out[g] = (float)(group_sums[g] / PATCHES);
}

extern "C" void kernel_launch(void* const* d_in, const int* in_sizes, int n_in,
                              void* d_out, int out_size, void* d_ws, size_t ws_size,
                              hipStream_t stream) {
    const float* x = (const float*)d_in[0];
    float* out = (float*)d_out;
    int* ws = (int*)d_ws;

    const int nimg = in_sizes[0] / NPIX;              // 2048
    const int ngroups = out_size;                     // 32

    hipMemsetAsync(ws, 0, ngroups * sizeof(int), stream);
    cc_kernel<<<nimg / IMGS_PER_BLOCK, 256, 0, stream>>>(x, ws);
    finalize_kernel<<<1, 64, 0, stream>>>(ws, out, ngroups);
}